// Round 1
// baseline (905.125 us; speedup 1.0000x reference)
//
#include <hip/hip_runtime.h>
#include <cmath>

#define NROWS 65536
#define EDIM  1024
#define KST   4

// LDS blob layout (floats): [0,5120)   Wp   as [d][e], d*1024+e
//                           [5120,10240) WiT as [d][e], 5120+d*1024+e
//                           [10240,11264) b_inv[e]
__global__ __launch_bounds__(256, 3) void rvq_fused(
    const float* __restrict__ h_in,    // (N,1024)
    const float* __restrict__ W_proj,  // (4,5,1024)
    const float* __restrict__ b_proj,  // (4,5)
    const float* __restrict__ W_inv,   // (4,1024,5)
    const float* __restrict__ b_inv,   // (4,1024)
    const float* __restrict__ temp,    // (1)
    const float* __restrict__ u,       // (4,N,5,8)
    const float* __restrict__ p,       // (N)
    float* __restrict__ out_q,         // (N,1024)
    float* __restrict__ out_code,      // (N,20)
    float* __restrict__ out_loss,      // (1)
    float shift012, float shift3)
{
    __shared__ float sW[11264];
    __shared__ float sLoss[4];

    const int tid  = threadIdx.x;
    const int lane = tid & 63;
    const int wib  = tid >> 6;
    const int wid  = blockIdx.x * 4 + wib;
    const int row0 = wid * 4;           // 4 rows per wave

    // ---- lane-role constants (d,c) grid; lanes 40..63 duplicate d=4 ----
    int dl = lane >> 3; if (dl > 4) dl = 4;
    const int   cl     = lane & 7;
    const float stepf  = (float)(cl - 4);
    const bool  valid  = (dl < 3) || (dl == 3 && cl >= 1 && cl <= 6)
                                  || (dl == 4 && cl >= 2 && cl <= 6);
    const float shiftd = (dl < 3) ? shift012 : ((dl == 3) ? shift3 : 0.0f);
    const float halfld = (dl < 3) ? 3.4965f : ((dl == 3) ? 2.4975f : 1.998f);
    const float offd   = (dl == 4) ? 0.0f : 0.5f;
    const float invhwd = (dl < 3) ? 0.25f : ((dl == 3) ? (1.0f/3.0f) : 0.5f);
    const int   ulane  = (lane < 40) ? lane : 39;

    const float tval = temp[0];
    const float te = fmaxf(tval * tval, 1e-8f);       // temp_eff
    const float inv_te  = 1.0f / te;                  // == alpha
    const float alpham1 = inv_te - 1.0f;

    // ---- load rows: element e = 4*lane + 256*j.  NOTE: no q accumulator
    // (out_q = h_in - r_final in the epilogue); no qi array (fused update).
    float4 r4[4][4];
    float  p_r[4];
    float  ss[4];
    #pragma unroll
    for (int rr = 0; rr < 4; ++rr) {
        const float4* src = (const float4*)(h_in + (size_t)(row0 + rr) * EDIM);
        #pragma unroll
        for (int j = 0; j < 4; ++j) r4[rr][j] = src[lane + 64 * j];
        p_r[rr] = p[row0 + rr];
        float s = 0.f;
        #pragma unroll
        for (int j = 0; j < 4; ++j) {
            s = fmaf(r4[rr][j].x, r4[rr][j].x, s);
            s = fmaf(r4[rr][j].y, r4[rr][j].y, s);
            s = fmaf(r4[rr][j].z, r4[rr][j].z, s);
            s = fmaf(r4[rr][j].w, r4[rr][j].w, s);
        }
        ss[rr] = (p_r[rr] <= 0.0f) ? s : 0.0f;   // p==0 edge: q_mix=0 -> ||h_in||
    }

    for (int i = 0; i < KST; ++i) {
        // ---- issue u loads early (independent of LDS/compute; ~1000cy of
        // staging+proj hide the HBM latency) ----
        float uu[4];
        #pragma unroll
        for (int rr = 0; rr < 4; ++rr)
            uu[rr] = u[(size_t)i * 2621440 + (size_t)(row0 + rr) * 40 + ulane];

        __syncthreads();   // protect LDS from previous stage's readers
        // ---- stage weights into LDS (no padding; all hot reads contiguous) ----
        {
            const float4* gp = (const float4*)(W_proj + (size_t)i * 5120);
            float4* sp = (float4*)sW;
            #pragma unroll
            for (int k = 0; k < 5; ++k) sp[tid + k * 256] = gp[tid + k * 256];
            // W_inv (1024,5) -> WiT [d][e]; e-major: each thread reads 5
            // consecutive floats, 5 conflict-free stores (distinct e per lane)
            const float* gi = W_inv + (size_t)i * 5120;
            #pragma unroll
            for (int m = 0; m < 4; ++m) {
                const int e = tid + m * 256;
                const float* sgi = gi + 5 * e;
                const float w0 = sgi[0], w1 = sgi[1], w2 = sgi[2], w3 = sgi[3], w4 = sgi[4];
                sW[5120 + e] = w0;
                sW[6144 + e] = w1;
                sW[7168 + e] = w2;
                sW[8192 + e] = w3;
                sW[9216 + e] = w4;
            }
            const float4* gb = (const float4*)(b_inv + (size_t)i * EDIM);
            ((float4*)(sW + 10240))[tid] = gb[tid];
        }
        __syncthreads();

        // ---- proj: h[d] = sum_e Wp[d][e] * r[e]  (identical FMA order) ----
        float acc[5][4];
        #pragma unroll
        for (int d = 0; d < 5; ++d)
            #pragma unroll
            for (int rr = 0; rr < 4; ++rr) acc[d][rr] = 0.f;

        #pragma unroll
        for (int d = 0; d < 5; ++d) {
            #pragma unroll
            for (int j = 0; j < 4; ++j) {
                const float4 w = *(const float4*)&sW[d * 1024 + 4 * lane + 256 * j];
                #pragma unroll
                for (int rr = 0; rr < 4; ++rr) {
                    float a = acc[d][rr];
                    a = fmaf(w.x, r4[rr][j].x, a);
                    a = fmaf(w.y, r4[rr][j].y, a);
                    a = fmaf(w.z, r4[rr][j].z, a);
                    a = fmaf(w.w, r4[rr][j].w, a);
                    acc[d][rr] = a;
                }
            }
        }
        // butterfly reduce (identical) + b_proj
        #pragma unroll
        for (int d = 0; d < 5; ++d) {
            const float bp = b_proj[i * 5 + d];
            #pragma unroll
            for (int rr = 0; rr < 4; ++rr) {
                float v = acc[d][rr];
                v += __shfl_xor(v, 1);
                v += __shfl_xor(v, 2);
                v += __shfl_xor(v, 4);
                v += __shfl_xor(v, 8);
                v += __shfl_xor(v, 16);
                v += __shfl_xor(v, 32);
                acc[d][rr] = v + bp;
            }
        }

        // ---- bound + gumbel-argmax (bit-identical math/order) ----
        float zq_mine[4];
        #pragma unroll
        for (int rr = 0; rr < 4; ++rr) {
            float hsel = acc[0][rr];
            hsel = (dl == 1) ? acc[1][rr] : hsel;
            hsel = (dl == 2) ? acc[2][rr] : hsel;
            hsel = (dl == 3) ? acc[3][rr] : hsel;
            hsel = (dl == 4) ? acc[4][rr] : hsel;
            const float z  = __fsub_rn(__fmul_rn(tanhf(hsel + shiftd), halfld), offd);
            const float g1 = logf(uu[rr] + 1e-20f);
            const float g  = -logf(-g1 + 1e-20f);
            const float df = __fsub_rn(z, stepf);
            float d2 = __fmul_rn(df, df);
            d2 = valid ? d2 : 1e8f;
            const float d2x = fmaf(alpham1, d2, d2);
            float y   = -(d2x * inv_te) + g;
            int   idx = cl;
            #pragma unroll
            for (int m = 1; m <= 4; m <<= 1) {     // argmax in 8-lane group
                const float yo = __shfl_xor(y, m);
                const int   io = __shfl_xor(idx, m);
                const bool take = (yo > y) || (yo == y && io < idx);
                y   = take ? yo : y;
                idx = take ? io : idx;
            }
            zq_mine[rr] = (float)(idx - 4) * invhwd;
        }
        if (lane < 40 && cl == 0) {
            #pragma unroll
            for (int rr = 0; rr < 4; ++rr)
                out_code[(size_t)(row0 + rr) * 20 + i * 5 + dl] = zq_mine[rr];
        }

        // broadcast zq[d][rr] into SGPRs (readlane, imm lane) -> no VGPR cost
        float zq[5][4];
        #pragma unroll
        for (int d = 0; d < 5; ++d)
            #pragma unroll
            for (int rr = 0; rr < 4; ++rr)
                zq[d][rr] = __int_as_float(
                    __builtin_amdgcn_readlane(__float_as_int(zq_mine[rr]), d * 8));

        // ---- inverse proj fused into r update; rounding identical:
        //      t = b_inv + zq0*w0 + ... + zq4*w4 ; r -= t  (single subtract) ----
        #pragma unroll
        for (int j = 0; j < 4; ++j) {
            const int eo = 4 * lane + 256 * j;
            const float4 b  = *(const float4*)&sW[10240 + eo];
            const float4 w0 = *(const float4*)&sW[5120 + eo];
            const float4 w1 = *(const float4*)&sW[6144 + eo];
            const float4 w2 = *(const float4*)&sW[7168 + eo];
            const float4 w3 = *(const float4*)&sW[8192 + eo];
            const float4 w4 = *(const float4*)&sW[9216 + eo];
            #pragma unroll
            for (int rr = 0; rr < 4; ++rr) {
                float tx = b.x, ty = b.y, tz = b.z, tw = b.w;
                tx = fmaf(zq[0][rr], w0.x, tx); ty = fmaf(zq[0][rr], w0.y, ty);
                tz = fmaf(zq[0][rr], w0.z, tz); tw = fmaf(zq[0][rr], w0.w, tw);
                tx = fmaf(zq[1][rr], w1.x, tx); ty = fmaf(zq[1][rr], w1.y, ty);
                tz = fmaf(zq[1][rr], w1.z, tz); tw = fmaf(zq[1][rr], w1.w, tw);
                tx = fmaf(zq[2][rr], w2.x, tx); ty = fmaf(zq[2][rr], w2.y, ty);
                tz = fmaf(zq[2][rr], w2.z, tz); tw = fmaf(zq[2][rr], w2.w, tw);
                tx = fmaf(zq[3][rr], w3.x, tx); ty = fmaf(zq[3][rr], w3.y, ty);
                tz = fmaf(zq[3][rr], w3.z, tz); tw = fmaf(zq[3][rr], w3.w, tw);
                tx = fmaf(zq[4][rr], w4.x, tx); ty = fmaf(zq[4][rr], w4.y, ty);
                tz = fmaf(zq[4][rr], w4.z, tz); tw = fmaf(zq[4][rr], w4.w, tw);
                r4[rr][j].x -= tx; r4[rr][j].y -= ty;
                r4[rr][j].z -= tz; r4[rr][j].w -= tw;
            }
        }

        // ---- loss snapshot: ||r||^2 at the selected stage ----
        const float lo = i * 0.25f, hi = (i + 1) * 0.25f;
        #pragma unroll
        for (int rr = 0; rr < 4; ++rr) {
            if (lo < p_r[rr] && p_r[rr] <= hi) {
                float s = 0.f;
                #pragma unroll
                for (int j = 0; j < 4; ++j) {
                    s = fmaf(r4[rr][j].x, r4[rr][j].x, s);
                    s = fmaf(r4[rr][j].y, r4[rr][j].y, s);
                    s = fmaf(r4[rr][j].z, r4[rr][j].z, s);
                    s = fmaf(r4[rr][j].w, r4[rr][j].w, s);
                }
                ss[rr] = s;
            }
        }
    }

    // ---- epilogue: out_q = h_in - r_final; loss reduce ----
    float4 h4[4][4];
    #pragma unroll
    for (int rr = 0; rr < 4; ++rr) {
        const float4* src = (const float4*)(h_in + (size_t)(row0 + rr) * EDIM);
        #pragma unroll
        for (int j = 0; j < 4; ++j) h4[rr][j] = src[lane + 64 * j];
    }
    float lsum = 0.f;
    #pragma unroll
    for (int rr = 0; rr < 4; ++rr) {
        float v = ss[rr];
        v += __shfl_xor(v, 1);
        v += __shfl_xor(v, 2);
        v += __shfl_xor(v, 4);
        v += __shfl_xor(v, 8);
        v += __shfl_xor(v, 16);
        v += __shfl_xor(v, 32);
        lsum += sqrtf(v);
    }
    #pragma unroll
    for (int rr = 0; rr < 4; ++rr) {
        float4* dst = (float4*)(out_q + (size_t)(row0 + rr) * EDIM);
        #pragma unroll
        for (int j = 0; j < 4; ++j) {
            float4 o;
            o.x = h4[rr][j].x - r4[rr][j].x;
            o.y = h4[rr][j].y - r4[rr][j].y;
            o.z = h4[rr][j].z - r4[rr][j].z;
            o.w = h4[rr][j].w - r4[rr][j].w;
            dst[lane + 64 * j] = o;
        }
    }
    if (lane == 0) sLoss[wib] = lsum;
    __syncthreads();
    if (tid == 0) {
        const float bl = (sLoss[0] + sLoss[1]) + (sLoss[2] + sLoss[3]);
        atomicAdd(out_loss, bl * (1.0f / 65536.0f));
    }
}

extern "C" void kernel_launch(void* const* d_in, const int* in_sizes, int n_in,
                              void* d_out, int out_size, void* d_ws, size_t ws_size,
                              hipStream_t stream) {
    (void)in_sizes; (void)n_in; (void)out_size; (void)d_ws; (void)ws_size;
    const float* h_in   = (const float*)d_in[0];
    const float* W_proj = (const float*)d_in[1];
    const float* b_proj = (const float*)d_in[2];
    const float* W_inv  = (const float*)d_in[3];
    const float* b_inv  = (const float*)d_in[4];
    const float* temp   = (const float*)d_in[5];
    const float* u      = (const float*)d_in[6];
    const float* p      = (const float*)d_in[7];

    float* out_q    = (float*)d_out;
    float* out_code = out_q + (size_t)NROWS * EDIM;
    float* out_loss = out_code + (size_t)NROWS * 20;

    // loss accumulator must start at 0 (d_out is poisoned before every call)
    hipMemsetAsync(out_loss, 0, sizeof(float), stream);

    // shift constants computed exactly as numpy does (f64 then cast)
    double hl01 = (8.0 - 1.0) * (1.0 - 1e-3) / 2.0;   // 3.4965
    double hl3  = (6.0 - 1.0) * (1.0 - 1e-3) / 2.0;   // 2.4975
    float shift012 = (float)std::tan(0.5 / hl01);
    float shift3   = (float)std::tan(0.5 / hl3);

    dim3 grid(NROWS / 16);   // 4 waves/block * 4 rows/wave
    dim3 block(256);
    hipLaunchKernelGGL(rvq_fused, grid, block, 0, stream,
                       h_in, W_proj, b_proj, W_inv, b_inv, temp, u, p,
                       out_q, out_code, out_loss, shift012, shift3);
}